// Round 3
// baseline (301.864 us; speedup 1.0000x reference)
//
#include <hip/hip_runtime.h>
#include <hip/hip_bf16.h>

#define NROWS 32768
#define DDIM  4096
#define ODIM  256
#define EPSV  1e-5f

#define CHUNKS 128
#define RPC    256      // rows per chunk (CHUNKS*RPC == NROWS)

#define BM 64
#define BK 64
#define NKT (DDIM / BK)

typedef __attribute__((ext_vector_type(4))) float          f32x4;
typedef __attribute__((ext_vector_type(8))) __bf16         bf16x8;
typedef __attribute__((ext_vector_type(8))) unsigned short u16x8;
typedef __attribute__((ext_vector_type(4))) unsigned short u16x4;

static __device__ __forceinline__ unsigned short f2bf(float f) {
  return __builtin_bit_cast(unsigned short, __float2bfloat16(f));
}

// ---------------- k1: per-chunk column partial sums ----------------
__global__ __launch_bounds__(256) void k1_stats(const float* __restrict__ x,
                                                float* __restrict__ psum,
                                                float* __restrict__ psq) {
  const int col = blockIdx.x * 1024 + threadIdx.x * 4;
  const float* p = x + (size_t)blockIdx.y * RPC * DDIM + col;
  f32x4 s = {0.f, 0.f, 0.f, 0.f};
  f32x4 q = {0.f, 0.f, 0.f, 0.f};
#pragma unroll 8
  for (int r = 0; r < RPC; ++r) {
    f32x4 v = *(const f32x4*)p;
    p += DDIM;
    s += v;
    q += v * v;
  }
  *(f32x4*)(psum + (size_t)blockIdx.y * DDIM + col) = s;
  *(f32x4*)(psq  + (size_t)blockIdx.y * DDIM + col) = q;
}

// ---------------- k2a: finalize mean/var -> scale/shift ----------------
__global__ __launch_bounds__(256) void k2_stats_finalize(
    const float* __restrict__ psum, const float* __restrict__ psq,
    const float* __restrict__ gamma, const float* __restrict__ beta,
    float* __restrict__ scale, float* __restrict__ shift) {
  __shared__ float ss[4][64];
  __shared__ float sq[4][64];
  const int lane = threadIdx.x & 63;
  const int g    = threadIdx.x >> 6;          // 0..3
  const int d    = blockIdx.x * 64 + lane;
  float s = 0.f, qq = 0.f;
  for (int c = g * 32; c < (g + 1) * 32; ++c) {
    s  += psum[(size_t)c * DDIM + d];
    qq += psq [(size_t)c * DDIM + d];
  }
  ss[g][lane] = s;
  sq[g][lane] = qq;
  __syncthreads();
  if (g == 0) {
    s  = ss[0][lane] + ss[1][lane] + ss[2][lane] + ss[3][lane];
    qq = sq[0][lane] + sq[1][lane] + sq[2][lane] + sq[3][lane];
    const float inv = 1.0f / (float)NROWS;
    const float mean = s * inv;
    const float var  = fmaxf(qq * inv - mean * mean, 0.f);
    const float a = gamma[d] * rsqrtf(var + EPSV);
    scale[d] = a;
    shift[d] = beta[d] - mean * a;
  }
}

// ---------------- k2b: W fp32 -> bf16 ----------------
__global__ __launch_bounds__(256) void k2_wconv(const float* __restrict__ Wf,
                                                unsigned short* __restrict__ Wb) {
  const size_t i = ((size_t)blockIdx.x * 256 + threadIdx.x) * 4;
  f32x4 v = *(const f32x4*)(Wf + i);
  u16x4 o;
  o[0] = f2bf(v[0]); o[1] = f2bf(v[1]); o[2] = f2bf(v[2]); o[3] = f2bf(v[3]);
  *(u16x4*)(Wb + i) = o;
}

// ---------------- k3: fused normalize+relu+bf16 GEMM ----------------
// C[n][o] = relu(a[d]*x[n][d]+c[d]) dot W[o][:] + b[o]
// BM=64 x BN=256, BK=64, 256 thr (4 waves, 1x4 of 64x64 wave tiles).
// 512 blocks -> 2 blocks/CU so barrier drains overlap across blocks
// (m97-style 2-barrier schedule, single LDS buffer, 40 KB/block).
__global__ __launch_bounds__(256, 2) void k3_bn_gemm(
    const float* __restrict__ x,
    const unsigned short* __restrict__ Wb,
    const float* __restrict__ scale,
    const float* __restrict__ shift,
    const float* __restrict__ bias,
    float* __restrict__ out) {
  __shared__ unsigned short As[BM * BK];     // 8 KB, XOR-swizzled
  __shared__ unsigned short Bs[ODIM * BK];   // 32 KB, XOR-swizzled

  const int tid = threadIdx.x;
  const int l   = tid & 63;
  const int w   = tid >> 6;     // 0..3 (wave col)
  const size_t bm0 = (size_t)blockIdx.x * BM;

  // --- A staging: thread covers row rA, 16 cols (2 x 8-elem units) ---
  const int rA = tid >> 2;            // 0..63
  const int uA = (tid & 3) * 2;       // unit 0,2,4,6
  const float* xp = x + (bm0 + rA) * (size_t)DDIM + uA * 8;
  const int sw = rA & 7;
  const int aw0 = rA * 64 + ((uA ^ sw) << 3);
  const int aw1 = rA * 64 + (((uA + 1) ^ sw) << 3);
  const float* sp = scale + uA * 8;
  const float* cp = shift + uA * 8;

  // --- B staging: 8 global_load_lds per thread, linear dest + pre-swizzled src
  const unsigned short* bsrc[8];
  unsigned short* bdst[8];
#pragma unroll
  for (int q = 0; q < 8; ++q) {
    const int p  = q * 256 + tid;     // 16B-unit index into Bs
    const int o  = p >> 3;            // W row 0..255
    const int up = p & 7;
    bsrc[q] = Wb + (size_t)o * DDIM + ((up ^ (o & 7)) << 3);
    bdst[q] = &Bs[(q * 256 + (tid & ~63)) * 8];   // wave-uniform base
  }

  // --- fragment LDS offsets (ushort units); kk=1 -> ^32 ---
  int offA[4], offB[4];
#pragma unroll
  for (int i = 0; i < 4; ++i) {
    const int row = i * 16 + (l & 15);
    offA[i] = row * 64 + (((l >> 4) ^ (row & 7)) << 3);
  }
#pragma unroll
  for (int j = 0; j < 4; ++j) {
    const int row = w * 64 + j * 16 + (l & 15);
    offB[j] = row * 64 + (((l >> 4) ^ (row & 7)) << 3);
  }

  const f32x4 zero = {0.f, 0.f, 0.f, 0.f};
  f32x4 acc[4][4];
#pragma unroll
  for (int i = 0; i < 4; ++i)
#pragma unroll
    for (int j = 0; j < 4; ++j) acc[i][j] = zero;

  for (int kt = 0; kt < NKT; ++kt) {
    // B tile: async global->LDS (16B per lane)
#pragma unroll
    for (int q = 0; q < 8; ++q) {
      __builtin_amdgcn_global_load_lds(
          (__attribute__((address_space(1))) void*)bsrc[q],
          (__attribute__((address_space(3))) void*)bdst[q], 16, 0, 0);
      bsrc[q] += BK;
    }
    // A tile: load fp32, affine+relu, cvt bf16, swizzled ds_write
    f32x4 sa0 = *(const f32x4*)sp;
    f32x4 sa1 = *(const f32x4*)(sp + 4);
    f32x4 sc0 = *(const f32x4*)cp;
    f32x4 sc1 = *(const f32x4*)(cp + 4);
    f32x4 v0 = *(const f32x4*)xp;
    f32x4 v1 = *(const f32x4*)(xp + 4);
    f32x4 v2 = *(const f32x4*)(xp + 8);
    f32x4 v3 = *(const f32x4*)(xp + 12);
    sp += BK; cp += BK; xp += BK;
    u16x8 pk0, pk1;
#pragma unroll
    for (int e = 0; e < 4; ++e) {
      pk0[e]     = f2bf(fmaxf(v0[e] * sa0[e] + sc0[e], 0.f));
      pk0[e + 4] = f2bf(fmaxf(v1[e] * sa1[e] + sc1[e], 0.f));
    }
    {
      f32x4 sa2 = *(const f32x4*)(sp - BK + 8);
      f32x4 sa3 = *(const f32x4*)(sp - BK + 12);
      f32x4 sc2 = *(const f32x4*)(cp - BK + 8);
      f32x4 sc3 = *(const f32x4*)(cp - BK + 12);
#pragma unroll
      for (int e = 0; e < 4; ++e) {
        pk1[e]     = f2bf(fmaxf(v2[e] * sa2[e] + sc2[e], 0.f));
        pk1[e + 4] = f2bf(fmaxf(v3[e] * sa3[e] + sc3[e], 0.f));
      }
    }
    *(u16x8*)&As[aw0] = pk0;
    *(u16x8*)&As[aw1] = pk1;

    __syncthreads();

#pragma unroll
    for (int kk = 0; kk < 2; ++kk) {
      const int kx = kk << 5;
      bf16x8 af[4], bfr[4];
#pragma unroll
      for (int i = 0; i < 4; ++i)
        af[i] = __builtin_bit_cast(bf16x8, *(const u16x8*)&As[offA[i] ^ kx]);
#pragma unroll
      for (int j = 0; j < 4; ++j)
        bfr[j] = __builtin_bit_cast(bf16x8, *(const u16x8*)&Bs[offB[j] ^ kx]);
#pragma unroll
      for (int i = 0; i < 4; ++i)
#pragma unroll
        for (int j = 0; j < 4; ++j)
          acc[i][j] = __builtin_amdgcn_mfma_f32_16x16x32_bf16(af[i], bfr[j], acc[i][j], 0, 0, 0);
    }

    __syncthreads();
  }

  // epilogue: C/D layout col=l&15, row=(l>>4)*4+rr
  const int cl = l & 15;
  const int rg = l >> 4;
#pragma unroll
  for (int j = 0; j < 4; ++j) {
    const int oc = w * 64 + j * 16 + cl;
    const float bv = bias[oc];
#pragma unroll
    for (int i = 0; i < 4; ++i) {
      const size_t r0 = bm0 + i * 16 + rg * 4;
#pragma unroll
      for (int rr = 0; rr < 4; ++rr) {
        out[(r0 + rr) * ODIM + oc] = acc[i][j][rr] + bv;
      }
    }
  }
}

extern "C" void kernel_launch(void* const* d_in, const int* in_sizes, int n_in,
                              void* d_out, int out_size, void* d_ws, size_t ws_size,
                              hipStream_t stream) {
  const float* x     = (const float*)d_in[0];
  const float* gamma = (const float*)d_in[1];
  const float* beta  = (const float*)d_in[2];
  const float* W     = (const float*)d_in[3];
  const float* b     = (const float*)d_in[4];
  float* out = (float*)d_out;

  float* psum  = (float*)d_ws;
  float* psq   = psum + (size_t)CHUNKS * DDIM;
  float* scale = psum + 2 * (size_t)CHUNKS * DDIM;
  float* shift = scale + DDIM;
  unsigned short* Wb = (unsigned short*)(shift + DDIM);

  k1_stats<<<dim3(4, CHUNKS), 256, 0, stream>>>(x, psum, psq);
  k2_stats_finalize<<<DDIM / 64, 256, 0, stream>>>(psum, psq, gamma, beta, scale, shift);
  k2_wconv<<<(ODIM * DDIM) / 1024, 256, 0, stream>>>(W, Wb);
  k3_bn_gemm<<<NROWS / BM, 256, 0, stream>>>(x, Wb, scale, shift, b, out);
}

// Round 4
// 239.258 us; speedup vs baseline: 1.2617x; 1.2617x over previous
//
#include <hip/hip_runtime.h>
#include <hip/hip_bf16.h>

#define NROWS 32768
#define DDIM  4096
#define ODIM  256
#define EPSV  1e-5f

#define CHUNKS 128
#define RPC    256      // rows per chunk (CHUNKS*RPC == NROWS)

#define BM 128
#define BK 64
#define NKT (DDIM / BK)   // 64 K-steps

typedef __attribute__((ext_vector_type(4))) float          f32x4;
typedef __attribute__((ext_vector_type(8))) __bf16         bf16x8;
typedef __attribute__((ext_vector_type(8))) unsigned short u16x8;
typedef __attribute__((ext_vector_type(4))) unsigned short u16x4;

static __device__ __forceinline__ unsigned short f2bf(float f) {
  return __builtin_bit_cast(unsigned short, __float2bfloat16(f));
}

// ---------------- k1: per-chunk column partial sums (R1-proven) ----------------
__global__ __launch_bounds__(256) void k1_stats(const float* __restrict__ x,
                                                float* __restrict__ psum,
                                                float* __restrict__ psq) {
  const int col = blockIdx.x * 1024 + threadIdx.x * 4;
  const float* p = x + (size_t)blockIdx.y * RPC * DDIM + col;
  f32x4 s = {0.f, 0.f, 0.f, 0.f};
  f32x4 q = {0.f, 0.f, 0.f, 0.f};
#pragma unroll 8
  for (int r = 0; r < RPC; ++r) {
    f32x4 v = *(const f32x4*)p;
    p += DDIM;
    s += v;
    q += v * v;
  }
  *(f32x4*)(psum + (size_t)blockIdx.y * DDIM + col) = s;
  *(f32x4*)(psq  + (size_t)blockIdx.y * DDIM + col) = q;
}

// ---------------- k2a: finalize mean/var -> scale/shift ----------------
__global__ __launch_bounds__(256) void k2_stats_finalize(
    const float* __restrict__ psum, const float* __restrict__ psq,
    const float* __restrict__ gamma, const float* __restrict__ beta,
    float* __restrict__ scale, float* __restrict__ shift) {
  __shared__ float ss[4][64];
  __shared__ float sq[4][64];
  const int lane = threadIdx.x & 63;
  const int g    = threadIdx.x >> 6;          // 0..3
  const int d    = blockIdx.x * 64 + lane;
  float s = 0.f, qq = 0.f;
  for (int c = g * 32; c < (g + 1) * 32; ++c) {
    s  += psum[(size_t)c * DDIM + d];
    qq += psq [(size_t)c * DDIM + d];
  }
  ss[g][lane] = s;
  sq[g][lane] = qq;
  __syncthreads();
  if (g == 0) {
    s  = ss[0][lane] + ss[1][lane] + ss[2][lane] + ss[3][lane];
    qq = sq[0][lane] + sq[1][lane] + sq[2][lane] + sq[3][lane];
    const float inv = 1.0f / (float)NROWS;
    const float mean = s * inv;
    const float var  = fmaxf(qq * inv - mean * mean, 0.f);
    const float a = gamma[d] * rsqrtf(var + EPSV);
    scale[d] = a;
    shift[d] = beta[d] - mean * a;
  }
}

// ---------------- k2b: W fp32 -> bf16 ----------------
__global__ __launch_bounds__(256) void k2_wconv(const float* __restrict__ Wf,
                                                unsigned short* __restrict__ Wb) {
  const size_t i = ((size_t)blockIdx.x * 256 + threadIdx.x) * 4;
  f32x4 v = *(const f32x4*)(Wf + i);
  u16x4 o;
  o[0] = f2bf(v[0]); o[1] = f2bf(v[1]); o[2] = f2bf(v[2]); o[3] = f2bf(v[3]);
  *(u16x4*)(Wb + i) = o;
}

// ---------------- k3: fused normalize+relu+bf16 GEMM, counted-vmcnt pipeline ---
// 128x256 tile, BK=64, 512 thr (8 waves, 2x4 of 64x64). Double-buffered LDS.
// Per step t: asm-issue A(t+1) (4x dwordx4) -> gl_lds B(t+1) -> MFMA(t)
//  -> vmcnt(4) [A done, B still in flight] -> transform+ds_write A(t+1)
//  -> vmcnt(0)+lgkmcnt(0) -> raw s_barrier.
__global__ __launch_bounds__(512, 1) void k3_bn_gemm(
    const float* __restrict__ x,
    const unsigned short* __restrict__ Wb,
    const float* __restrict__ scale,
    const float* __restrict__ shift,
    const float* __restrict__ bias,
    float* __restrict__ out) {
  __shared__ unsigned short As[2][BM * BK];     // 2 x 16 KB, XOR-swizzled
  __shared__ unsigned short Bs[2][ODIM * BK];   // 2 x 32 KB, XOR-swizzled
  __shared__ float SF[DDIM];                    // 16 KB scale
  __shared__ float SH[DDIM];                    // 16 KB shift

  const int tid = threadIdx.x;
  const int l   = tid & 63;
  const int w   = tid >> 6;     // 0..7
  const int wr  = w >> 2;       // 0..1
  const int wc  = w & 3;        // 0..3
  const size_t bm0 = (size_t)blockIdx.x * BM;

  // --- scale/shift LDS preload (1024 f32x4 over 512 threads) ---
  ((f32x4*)SF)[tid * 2]     = ((const f32x4*)scale)[tid * 2];
  ((f32x4*)SF)[tid * 2 + 1] = ((const f32x4*)scale)[tid * 2 + 1];
  ((f32x4*)SH)[tid * 2]     = ((const f32x4*)shift)[tid * 2];
  ((f32x4*)SH)[tid * 2 + 1] = ((const f32x4*)shift)[tid * 2 + 1];

  // --- A staging geometry: thread covers rows rA, rA+64; 8-col unit uA ---
  const int rA = tid >> 3;      // 0..63
  const int uA = tid & 7;       // 0..7
  const float* xp0 = x + (bm0 + rA) * (size_t)DDIM + uA * 8;
  const float* xp1 = xp0 + (size_t)64 * DDIM;
  const int awo = rA * 64 + ((uA ^ (rA & 7)) << 3);   // ushort offset in buf
  int ktb = uA * 8;                                   // scale/shift col base

  // --- B staging: gl_lds, linear LDS dest + inverse-swizzled global src ---
  const unsigned short* bsrc[4];
#pragma unroll
  for (int q = 0; q < 4; ++q) {
    const int p  = w * 256 + q * 64 + l;   // 16B-unit index into a B buffer
    const int o  = p >> 3;
    const int up = p & 7;
    bsrc[q] = Wb + (size_t)o * DDIM + ((up ^ (o & 7)) << 3);
  }

  // --- fragment LDS offsets (ushort units, within one buffer); kk -> ^32 ---
  int offA[4], offB[4];
#pragma unroll
  for (int i = 0; i < 4; ++i) {
    const int row = wr * 64 + i * 16 + (l & 15);
    offA[i] = row * 64 + (((l >> 4) ^ (row & 7)) << 3);
  }
#pragma unroll
  for (int j = 0; j < 4; ++j) {
    const int row = wc * 64 + j * 16 + (l & 15);
    offB[j] = row * 64 + (((l >> 4) ^ (row & 7)) << 3);
  }

  const f32x4 zero = {0.f, 0.f, 0.f, 0.f};
  f32x4 acc[4][4];
#pragma unroll
  for (int i = 0; i < 4; ++i)
#pragma unroll
    for (int j = 0; j < 4; ++j) acc[i][j] = zero;

#define ISSUE_A(V00, V01, V10, V11)                                            \
  asm volatile("global_load_dwordx4 %0, %1, off" : "=v"(V00) : "v"(xp0));      \
  asm volatile("global_load_dwordx4 %0, %1, off" : "=v"(V01) : "v"(xp0 + 4));  \
  asm volatile("global_load_dwordx4 %0, %1, off" : "=v"(V10) : "v"(xp1));      \
  asm volatile("global_load_dwordx4 %0, %1, off" : "=v"(V11) : "v"(xp1 + 4));  \
  asm volatile("" ::: "memory");

#define ISSUE_B(BUFI)                                                          \
  _Pragma("unroll")                                                            \
  for (int q = 0; q < 4; ++q) {                                                \
    __builtin_amdgcn_global_load_lds(                                          \
        (__attribute__((address_space(1))) void*)bsrc[q],                      \
        (__attribute__((address_space(3))) void*)(                             \
            &Bs[BUFI][(w * 256 + q * 64) * 8]),                                \
        16, 0, 0);                                                             \
    bsrc[q] += BK;                                                             \
  }

#define TRANSFORM_WRITE(BUFI, V00, V01, V10, V11)                              \
  {                                                                            \
    f32x4 sa0 = *(const f32x4*)&SF[ktb];                                       \
    f32x4 sa1 = *(const f32x4*)&SF[ktb + 4];                                   \
    f32x4 sc0 = *(const f32x4*)&SH[ktb];                                       \
    f32x4 sc1 = *(const f32x4*)&SH[ktb + 4];                                   \
    ktb += BK;                                                                 \
    u16x8 pk0, pk1;                                                            \
    _Pragma("unroll")                                                          \
    for (int e = 0; e < 4; ++e) {                                              \
      pk0[e]     = f2bf(fmaxf(V00[e] * sa0[e] + sc0[e], 0.f));                 \
      pk0[e + 4] = f2bf(fmaxf(V01[e] * sa1[e] + sc1[e], 0.f));                 \
      pk1[e]     = f2bf(fmaxf(V10[e] * sa0[e] + sc0[e], 0.f));                 \
      pk1[e + 4] = f2bf(fmaxf(V11[e] * sa1[e] + sc1[e], 0.f));                 \
    }                                                                          \
    *(u16x8*)&As[BUFI][awo]        = pk0;                                      \
    *(u16x8*)&As[BUFI][awo + 4096] = pk1;                                      \
  }

#define MFMA_PHASE(BUFI)                                                       \
  _Pragma("unroll")                                                            \
  for (int kk = 0; kk < 2; ++kk) {                                             \
    const int kx = kk << 5;                                                    \
    bf16x8 af[4], bfr[4];                                                      \
    _Pragma("unroll")                                                          \
    for (int i = 0; i < 4; ++i)                                                \
      af[i] = __builtin_bit_cast(bf16x8,                                       \
                                 *(const u16x8*)&As[BUFI][offA[i] ^ kx]);      \
    _Pragma("unroll")                                                          \
    for (int j = 0; j < 4; ++j)                                                \
      bfr[j] = __builtin_bit_cast(bf16x8,                                      \
                                  *(const u16x8*)&Bs[BUFI][offB[j] ^ kx]);     \
    _Pragma("unroll")                                                          \
    for (int i = 0; i < 4; ++i)                                                \
      _Pragma("unroll")                                                        \
      for (int j = 0; j < 4; ++j)                                              \
        acc[i][j] = __builtin_amdgcn_mfma_f32_16x16x32_bf16(                   \
            af[i], bfr[j], acc[i][j], 0, 0, 0);                                \
  }

  // ---- prologue: stage tile 0 into buffers [0] ----
  {
    f32x4 v00, v01, v10, v11;
    ISSUE_A(v00, v01, v10, v11);
    ISSUE_B(0);
    xp0 += BK; xp1 += BK;
    // scale/shift LDS stores visible before any thread reads them
    asm volatile("s_waitcnt lgkmcnt(0)" ::: "memory");
    __builtin_amdgcn_sched_barrier(0);
    __builtin_amdgcn_s_barrier();
    asm volatile("s_waitcnt vmcnt(4)" ::: "memory");   // A0 done, B0 in flight
    __builtin_amdgcn_sched_barrier(0);
    TRANSFORM_WRITE(0, v00, v01, v10, v11);
    asm volatile("s_waitcnt vmcnt(0) lgkmcnt(0)" ::: "memory");
    __builtin_amdgcn_sched_barrier(0);
    __builtin_amdgcn_s_barrier();
  }

#define STEP(CUR, PF)                                                          \
  do {                                                                         \
    f32x4 v00, v01, v10, v11;                                                  \
    if (PF) {                                                                  \
      ISSUE_A(v00, v01, v10, v11);                                             \
      ISSUE_B((CUR) ^ 1);                                                      \
      xp0 += BK; xp1 += BK;                                                    \
    }                                                                          \
    MFMA_PHASE(CUR);                                                           \
    if (PF) {                                                                  \
      asm volatile("s_waitcnt vmcnt(4)" ::: "memory");                         \
      __builtin_amdgcn_sched_barrier(0);                                       \
      TRANSFORM_WRITE((CUR) ^ 1, v00, v01, v10, v11);                          \
    }                                                                          \
    asm volatile("s_waitcnt vmcnt(0) lgkmcnt(0)" ::: "memory");                \
    __builtin_amdgcn_sched_barrier(0);                                         \
    __builtin_amdgcn_s_barrier();                                              \
  } while (0)

  // steps 0..61
  for (int kt = 0; kt < NKT - 2; kt += 2) {
    STEP(0, true);
    STEP(1, true);
  }
  STEP(0, true);    // step 62, prefetch tile 63 into buf 1
  STEP(1, false);   // step 63
#undef STEP
#undef MFMA_PHASE
#undef TRANSFORM_WRITE
#undef ISSUE_B
#undef ISSUE_A

  // epilogue: C/D layout col=l&15, row=(l>>4)*4+rr
  const int cl = l & 15;
  const int rg = l >> 4;
#pragma unroll
  for (int j = 0; j < 4; ++j) {
    const int oc = wc * 64 + j * 16 + cl;
    const float bv = bias[oc];
#pragma unroll
    for (int i = 0; i < 4; ++i) {
      const size_t r0 = bm0 + wr * 64 + i * 16 + rg * 4;
#pragma unroll
      for (int rr = 0; rr < 4; ++rr) {
        out[(r0 + rr) * ODIM + oc] = acc[i][j][rr] + bv;
      }
    }
  }
}

extern "C" void kernel_launch(void* const* d_in, const int* in_sizes, int n_in,
                              void* d_out, int out_size, void* d_ws, size_t ws_size,
                              hipStream_t stream) {
  const float* x     = (const float*)d_in[0];
  const float* gamma = (const float*)d_in[1];
  const float* beta  = (const float*)d_in[2];
  const float* W     = (const float*)d_in[3];
  const float* b     = (const float*)d_in[4];
  float* out = (float*)d_out;

  float* psum  = (float*)d_ws;
  float* psq   = psum + (size_t)CHUNKS * DDIM;
  float* scale = psum + 2 * (size_t)CHUNKS * DDIM;
  float* shift = scale + DDIM;
  unsigned short* Wb = (unsigned short*)(shift + DDIM);

  k1_stats<<<dim3(4, CHUNKS), 256, 0, stream>>>(x, psum, psq);
  k2_stats_finalize<<<DDIM / 64, 256, 0, stream>>>(psum, psq, gamma, beta, scale, shift);
  k2_wconv<<<(ODIM * DDIM) / 1024, 256, 0, stream>>>(W, Wb);
  k3_bn_gemm<<<NROWS / BM, 512, 0, stream>>>(x, Wb, scale, shift, b, out);
}